// Round 9
// baseline (367.204 us; speedup 1.0000x reference)
//
#include <hip/hip_runtime.h>
#include <math.h>

#define NN 2048
#define DD 128
#define EDIM 8
#define EHID 32
#define DHH 16

typedef __attribute__((address_space(1))) const void GV;
typedef __attribute__((address_space(3))) void LV;

#define NB 6        // ring slots
#define NSTEP 256   // 2048 / 8 j's per step
#define RROWS 4     // rows per block

// ---------------- Kernel 1: Q,K,V projections + folded edge projection QW ----
__global__ __launch_bounds__(384) void proj_kernel(
    const float* __restrict__ X,
    const float* __restrict__ Wq, const float* __restrict__ Wk,
    const float* __restrict__ Wv, const float* __restrict__ We,
    const float* __restrict__ Wr,
    float* __restrict__ Qo, float* __restrict__ Ko,
    float* __restrict__ Vo, float* __restrict__ QWo) {
  __shared__ float x_lds[2][128];
  __shared__ float wer_lds[8][128];
  __shared__ float q_lds[2][128];
  const int t = threadIdx.x;
  const int i0 = blockIdx.x * 2;

  if (t < 256) x_lds[t >> 7][t & 127] = X[(size_t)i0 * 128 + t];

  if (t < 128) {
    float acc[EDIM];
#pragma unroll
    for (int e = 0; e < EDIM; ++e) acc[e] = 0.f;
    for (int k = 0; k < EHID; ++k) {
      const float wr = Wr[k * 128 + t];
#pragma unroll
      for (int e = 0; e < EDIM; ++e) acc[e] = fmaf(We[e * EHID + k], wr, acc[e]);
    }
#pragma unroll
    for (int e = 0; e < EDIM; ++e) wer_lds[e][t] = acc[e];
  }
  __syncthreads();

  const int mat = t >> 7;
  const int c = t & 127;
  const float* __restrict__ W = (mat == 0) ? Wq : ((mat == 1) ? Wk : Wv);
  float a0 = 0.f, a1 = 0.f;
#pragma unroll 8
  for (int d = 0; d < 128; ++d) {
    const float w = W[d * 128 + c];
    a0 = fmaf(x_lds[0][d], w, a0);
    a1 = fmaf(x_lds[1][d], w, a1);
  }
  float* __restrict__ Out = (mat == 0) ? Qo : ((mat == 1) ? Ko : Vo);
  Out[(size_t)i0 * 128 + c] = a0;
  Out[(size_t)(i0 + 1) * 128 + c] = a1;
  if (mat == 0) { q_lds[0][c] = a0; q_lds[1][c] = a1; }
  __syncthreads();

  if (t < 64) {
    const int h = t >> 3, e = t & 7;
#pragma unroll
    for (int r = 0; r < 2; ++r) {
      float s = 0.f;
#pragma unroll
      for (int d = 0; d < DHH; ++d)
        s = fmaf(q_lds[r][h * DHH + d], wer_lds[e][h * DHH + d], s);
      QWo[(size_t)(i0 + r) * 64 + h * 8 + e] = s;
    }
  }
}

#define DOT4ADD(S, A, B) do {            \
    S = fmaf((A).x, (B).x, S);           \
    S = fmaf((A).y, (B).y, S);           \
    S = fmaf((A).z, (B).z, S);           \
    S = fmaf((A).w, (B).w, S); } while (0)

// ---------------- Kernel 2: deep-ring producer/consumer attention -----------
// grid 512 (4 rows each), 320 threads: t<256 consumers (il4,h8,js8),
// wave 4 = producer staging K/V/E/adj for step s+5 (10 gl_lds per slot,
// vmcnt(40) steady -> 4-step issue->use distance). Consumer LDS reads use
// XOR'd part index (n^hs) so each ds_read_b128 inst covers all 8 bank quads.
__global__ __launch_bounds__(320) void attn_kernel(
    const float* __restrict__ Qg, const float* __restrict__ Kg,
    const float* __restrict__ Vg, const float* __restrict__ QWg,
    const int* __restrict__ adj, const float* __restrict__ Eg,
    const float* __restrict__ Wo, float* __restrict__ out) {
  __shared__ float4 KL[NB][256];   // 24 KB: [slot][js*32 + h*4 + part]
  __shared__ float4 VL[NB][256];   // 24 KB
  __shared__ float4 EL[NB][64];    // 6 KB:  [slot][il*16 + js*2 + half]
  __shared__ int    AL[NB][64];    // 1.5 KB: [slot][il*16 + js]
  __shared__ float  mbuf[128 * 18];
  __shared__ float  o_lds[4][128];

  const int t = threadIdx.x;
  const int i0 = blockIdx.x * RROWS;

  float acc[16];
#pragma unroll
  for (int d = 0; d < 16; ++d) acc[d] = 0.f;
  float m = -INFINITY, mt = -INFINITY, l = 0.f;

  if (t >= 256) {
    // ======================= producer wave =======================
    const int ln = t - 256;
    const float* kS = Kg + (size_t)(ln >> 5) * 128 + (ln & 31) * 4;
    const float* vS = Vg + (size_t)(ln >> 5) * 128 + (ln & 31) * 4;
    const float* eS = Eg + ((size_t)(i0 + (ln >> 4)) * NN + ((ln >> 1) & 7)) * 8
                         + (ln & 1) * 4;
    const int jsA = ((ln & 15) > 7) ? 7 : (ln & 15);
    const int* aS = adj + (size_t)(i0 + (ln >> 4)) * NN + jsA;

    auto ISSUE = [&](int sl, int j0) {
#pragma unroll
      for (int p = 0; p < 4; ++p)
        __builtin_amdgcn_global_load_lds((GV*)(kS + (size_t)(j0 + p * 2) * 128),
                                         (LV*)&KL[sl][p * 64], 16, 0, 0);
#pragma unroll
      for (int p = 0; p < 4; ++p)
        __builtin_amdgcn_global_load_lds((GV*)(vS + (size_t)(j0 + p * 2) * 128),
                                         (LV*)&VL[sl][p * 64], 16, 0, 0);
      __builtin_amdgcn_global_load_lds((GV*)(eS + (size_t)j0 * 8),
                                       (LV*)&EL[sl][0], 16, 0, 0);
      __builtin_amdgcn_global_load_lds((GV*)(aS + j0), (LV*)&AL[sl][0], 4, 0, 0);
    };

    ISSUE(0, 0); ISSUE(1, 8); ISSUE(2, 16); ISSUE(3, 24); ISSUE(4, 32);
    asm volatile("s_waitcnt vmcnt(40)" ::: "memory");   // slot 0 complete
    __builtin_amdgcn_sched_barrier(0);
    __builtin_amdgcn_s_barrier();

    int ip = 5, jI = 40;
    for (int s = 0; s < NSTEP; ++s) {
      if (s <= 250) {
        ISSUE(ip, jI);
        jI += 8;
        if (++ip == NB) ip = 0;
        asm volatile("s_waitcnt vmcnt(40)" ::: "memory");
      } else if (s == 251) {
        asm volatile("s_waitcnt vmcnt(30)" ::: "memory");
      } else if (s == 252) {
        asm volatile("s_waitcnt vmcnt(20)" ::: "memory");
      } else if (s == 253) {
        asm volatile("s_waitcnt vmcnt(10)" ::: "memory");
      } else {
        asm volatile("s_waitcnt vmcnt(0)" ::: "memory");
      }
      __builtin_amdgcn_sched_barrier(0);
      __builtin_amdgcn_s_barrier();
    }
  } else {
    // ======================= consumer waves =======================
    const int il = t & 3;
    const int h = (t >> 2) & 7;
    const int js = t >> 5;
    const int hs = (h >> 1) & 3;      // K/V part-XOR
    const int hb = il & 1;            // E half-XOR
    const int i = i0 + il;

    float4 qq0, qq1, qq2, qq3, qw0, qw1;
    {
      const float4* qp = (const float4*)(Qg + (size_t)i * 128 + h * 16);
      qq0 = qp[0 ^ hs]; qq1 = qp[1 ^ hs]; qq2 = qp[2 ^ hs]; qq3 = qp[3 ^ hs];
      const float4* wp = (const float4*)(QWg + (size_t)i * 64 + h * 8);
      qw0 = wp[0 ^ hb]; qw1 = wp[1 ^ hb];
    }

    const int kOff = js * 32 + h * 4;
    const int eOff = il * 16 + js * 2;
    const int aOff = il * 16 + js;

    __builtin_amdgcn_s_barrier();     // prologue: slot 0 ready
    __builtin_amdgcn_sched_barrier(0);

    int sl = 0;
    for (int s = 0; s < NSTEP; ++s) {
      const int a = AL[sl][aOff];
      const float4 kk0 = KL[sl][kOff + (0 ^ hs)];
      const float4 kk1 = KL[sl][kOff + (1 ^ hs)];
      const float4 kk2 = KL[sl][kOff + (2 ^ hs)];
      const float4 kk3 = KL[sl][kOff + (3 ^ hs)];
      const float4 ee0 = EL[sl][eOff + (0 ^ hb)];
      const float4 ee1 = EL[sl][eOff + (1 ^ hb)];
      const float4 vv0 = VL[sl][kOff + (0 ^ hs)];
      const float4 vv1 = VL[sl][kOff + (1 ^ hs)];
      const float4 vv2 = VL[sl][kOff + (2 ^ hs)];
      const float4 vv3 = VL[sl][kOff + (3 ^ hs)];

      float s0 = 0.f, s1 = 0.f, b0 = 0.f;
      DOT4ADD(s0, qq0, kk0); DOT4ADD(s0, qq1, kk1);
      DOT4ADD(s1, qq2, kk2); DOT4ADD(s1, qq3, kk3);
      DOT4ADD(b0, qw0, ee0); DOT4ADD(b0, qw1, ee1);
      const float raw = (s0 + s1) + b0;
      // scale(1/4) + leaky(0.2) + log2e folded (exact: leaky pos-homogeneous)
      float sc2 = fmaf(0.14426950f, fabsf(raw), 0.21640425f * raw);
      sc2 = (a > 0) ? sc2 : -1e9f;
      if (sc2 > mt) {                 // deferred-rescale online softmax
        const float rr = exp2f(m - sc2);
        l *= rr;
#pragma unroll
        for (int d = 0; d < 16; ++d) acc[d] *= rr;
        m = sc2; mt = sc2 + 12.f;
      }
      const float p = exp2f(sc2 - m);
      l += p;
      acc[0]  = fmaf(p, vv0.x, acc[0]);  acc[1]  = fmaf(p, vv0.y, acc[1]);
      acc[2]  = fmaf(p, vv0.z, acc[2]);  acc[3]  = fmaf(p, vv0.w, acc[3]);
      acc[4]  = fmaf(p, vv1.x, acc[4]);  acc[5]  = fmaf(p, vv1.y, acc[5]);
      acc[6]  = fmaf(p, vv1.z, acc[6]);  acc[7]  = fmaf(p, vv1.w, acc[7]);
      acc[8]  = fmaf(p, vv2.x, acc[8]);  acc[9]  = fmaf(p, vv2.y, acc[9]);
      acc[10] = fmaf(p, vv2.z, acc[10]); acc[11] = fmaf(p, vv2.w, acc[11]);
      acc[12] = fmaf(p, vv3.x, acc[12]); acc[13] = fmaf(p, vv3.y, acc[13]);
      acc[14] = fmaf(p, vv3.z, acc[14]); acc[15] = fmaf(p, vv3.w, acc[15]);

      __builtin_amdgcn_sched_barrier(0);
      __builtin_amdgcn_s_barrier();
      __builtin_amdgcn_sched_barrier(0);
      if (++sl == NB) sl = 0;
    }
  }

  // ================= merge js-partials (all 320 threads pass barriers) =====
  const int ilc = t & 3, hc = (t >> 2) & 7, jsc = t >> 5;
  const int hsc = (hc >> 1) & 3;
  const int u = t & 31;               // il + 4*h
  for (int k = 4; k >= 1; k >>= 1) {
    if (t < 256 && jsc >= k && jsc < 2 * k) {
      float* b = mbuf + ((size_t)((jsc - k) * 32 + u)) * 18;
      b[0] = m; b[1] = l;
#pragma unroll
      for (int d = 0; d < 16; ++d) b[2 + d] = acc[d];
    }
    __syncthreads();
    if (t < 256 && jsc < k) {
      const float* b = mbuf + ((size_t)(jsc * 32 + u)) * 18;
      const float m2 = b[0], l2 = b[1];
      const float M = fmaxf(m, m2);
      const float sa = exp2f(m - M), sb = exp2f(m2 - M);
      l = l * sa + l2 * sb;
#pragma unroll
      for (int d = 0; d < 16; ++d) acc[d] = acc[d] * sa + b[2 + d] * sb;
      m = M;
    }
    __syncthreads();
  }
  if (t < 256 && jsc == 0) {
    const float inv = 1.f / l;
#pragma unroll
    for (int n = 0; n < 4; ++n) {     // un-permute: acc part n holds logical n^hs
      const int cb = hc * 16 + ((n ^ hsc) << 2);
      o_lds[ilc][cb + 0] = acc[4 * n + 0] * inv;
      o_lds[ilc][cb + 1] = acc[4 * n + 1] * inv;
      o_lds[ilc][cb + 2] = acc[4 * n + 2] * inv;
      o_lds[ilc][cb + 3] = acc[4 * n + 3] * inv;
    }
  }
  __syncthreads();

  if (t < 256) {                      // epilogue: out = O @ Wo (2 rows/thread)
    const int rr = t >> 7, c = t & 127;
    float d0 = 0.f, d1 = 0.f;
#pragma unroll 8
    for (int d = 0; d < 128; ++d) {
      const float w = Wo[d * 128 + c];
      d0 = fmaf(o_lds[rr][d], w, d0);
      d1 = fmaf(o_lds[rr + 2][d], w, d1);
    }
    out[(size_t)(i0 + rr) * 128 + c] = d0;
    out[(size_t)(i0 + rr + 2) * 128 + c] = d1;
  }
}

extern "C" void kernel_launch(void* const* d_in, const int* in_sizes, int n_in,
                              void* d_out, int out_size, void* d_ws, size_t ws_size,
                              hipStream_t stream) {
  const float* X   = (const float*)d_in[0];
  const int*   adj = (const int*)d_in[1];
  const float* E   = (const float*)d_in[2];
  const float* Wq  = (const float*)d_in[3];
  const float* Wk  = (const float*)d_in[4];
  const float* Wv  = (const float*)d_in[5];
  const float* We  = (const float*)d_in[6];
  const float* Wr  = (const float*)d_in[7];
  const float* Wo  = (const float*)d_in[8];
  float* out = (float*)d_out;

  float* Qs  = (float*)d_ws;
  float* Ks  = Qs + (size_t)NN * DD;
  float* Vs  = Ks + (size_t)NN * DD;
  float* QWs = Vs + (size_t)NN * DD;

  hipLaunchKernelGGL(proj_kernel, dim3(NN / 2), dim3(384), 0, stream,
                     X, Wq, Wk, Wv, We, Wr, Qs, Ks, Vs, QWs);
  hipLaunchKernelGGL(attn_kernel, dim3(NN / RROWS), dim3(320), 0, stream,
                     Qs, Ks, Vs, QWs, adj, E, Wo, out);
}